// Round 2
// baseline (1760.017 us; speedup 1.0000x reference)
//
#include <hip/hip_runtime.h>
#include <hip/hip_bf16.h>
#include <math.h>

#define H_DIM  1152
#define FL_DIM 1152
#define FH_DIM 4608
#define NTOK   32768
#define FL_PAD 1280   // light N padded to 5*256 (gemm1 B rows)
#define H_PAD  1280   // gemm2 out-cols padded to 5*256 (W2 rows)

typedef __attribute__((ext_vector_type(8))) short bf16x8;
typedef __attribute__((ext_vector_type(4))) float floatx4;
typedef __attribute__((ext_vector_type(4))) unsigned short ushort4v;

__device__ __forceinline__ unsigned short f2bf(float f) {
  union { float f; unsigned int i; } v; v.f = f;
  return (unsigned short)((v.i + 0x7FFFu + ((v.i >> 16) & 1u)) >> 16);
}

// ---------------- fp32 -> bf16 conversion (weights) -------------------------
__global__ __launch_bounds__(256) void cvt_kernel(
    const float* __restrict__ in, unsigned short* __restrict__ out, int n4) {
  const int i = blockIdx.x * 256 + threadIdx.x;
  if (i >= n4) return;
  const float4 v = ((const float4*)in)[i];
  ushort4v o;
  o[0] = f2bf(v.x); o[1] = f2bf(v.y); o[2] = f2bf(v.z); o[3] = f2bf(v.w);
  ((ushort4v*)out)[i] = o;
}

// ------- router + x cvt: p1[t] = sigmoid(l1-l0); xb = bf16(x) ---------------
__global__ __launch_bounds__(256) void router_cvt_kernel(
    const float* __restrict__ x,   // [NTOK, H] fp32
    const float* __restrict__ rw,  // [2, H]
    const float* __restrict__ rb,  // [2]
    float* __restrict__ p1out,     // [NTOK]
    unsigned short* __restrict__ xb) {  // [NTOK, H] bf16
  const int wave = threadIdx.x >> 6;
  const int lane = threadIdx.x & 63;
  const int tok = blockIdx.x * 4 + wave;
  const float* xr = x + (size_t)tok * H_DIM;
  unsigned short* xo = xb + (size_t)tok * H_DIM;
  float s0 = 0.f, s1 = 0.f;
#pragma unroll
  for (int j = 0; j < H_DIM / 64; ++j) {
    const int h = j * 64 + lane;
    const float xv = xr[h];
    xo[h] = f2bf(xv);
    s0 += xv * rw[h];
    s1 += xv * rw[H_DIM + h];
  }
  for (int off = 32; off > 0; off >>= 1) {
    s0 += __shfl_down(s0, off);
    s1 += __shfl_down(s1, off);
  }
  if (lane == 0) {
    const float l0 = s0 + rb[0];
    const float l1 = s1 + rb[1];
    p1out[tok] = 1.f / (1.f + expf(l0 - l1));
  }
}

// ============ 256x256 software-pipelined 4-phase GEMM (BK=64) ===============
// 512 threads = 8 waves (2m x 4n), per-wave output 128x64 (8x4 16x16 frags).
// LDS: A[2]+B[2] of 256x64 bf16 = 128 KiB double buffer, XOR-swizzled chunks.
// REGISTER PIPELINE (the round-1 fix): phase p's MFMA consumes frags ds_read
// in phase p-1, so the compiler-emitted lgkm wait before each MFMA cluster is
// for already-landed reads -> LDS throughput hides under MFMA.
//   tile t, phase q computes quadrant q (m-frags 2q,2q+1 x all n x K=64):
//     P0: rd af(q1)            | stage A(t+1) h0 | bar | mma q0 | bar
//     P1: rd af(q2)            | stage A(t+1) h1 | bar | mma q1 | vmcnt(4) bar
//     P2: rd af(q3)+bn[B(t+1) n01] | stage B(t+2) h0 | bar | mma q2 | vmcnt(2) bar
//     P3: rd af(t+1 q0)+bn[n23]    | stage B(t+2) h1 | bar | mma q3 | bar
//   vmcnt(4)@P1: drains B(t+1) (staged t-1 P2/P3) before its reg-prefetch,
//   keeps A(t+1)'s 4 loads in flight. vmcnt(2)@P2: drains A(t+1), keeps
//   B(t+2)h0. Never 0 in steady state. Tails peeled via <SA,SB> templates.

struct Offs { int o0, o1, o2, o3; };

__device__ __forceinline__ Offs make_offs(int tid, int lda) {
  Offs o;
  const int c0 = tid, c1 = 512 + tid, c2 = 1024 + tid, c3 = 1536 + tid;
  const int r0 = c0 >> 3, r1 = c1 >> 3, r2 = c2 >> 3, r3 = c3 >> 3;
  o.o0 = r0 * lda + (((c0 & 7) ^ (r0 & 7)) << 3);
  o.o1 = r1 * lda + (((c1 & 7) ^ (r1 & 7)) << 3);
  o.o2 = r2 * lda + (((c2 & 7) ^ (r2 & 7)) << 3);
  o.o3 = r3 * lda + (((c3 & 7) ^ (r3 & 7)) << 3);
  return o;
}

__device__ __forceinline__ void stage_slot(const unsigned short* g, int off,
                                           unsigned short* lds, int slot, int w) {
  __builtin_amdgcn_global_load_lds(
      (const __attribute__((address_space(1))) void*)(g + off),
      (__attribute__((address_space(3))) void*)(lds + slot * 4096 + w * 512),
      16, 0, 0);
}

__device__ __forceinline__ void stage4(const unsigned short* g, const Offs& o,
                                       unsigned short* lds, int w) {
  stage_slot(g, o.o0, lds, 0, w);
  stage_slot(g, o.o1, lds, 1, w);
  stage_slot(g, o.o2, lds, 2, w);
  stage_slot(g, o.o3, lds, 3, w);
}

// LDS frag reads: row&7 == l16&7 for every frag a wave touches, so the chunk
// XOR collapses to two per-lane base offsets (ch0/ch1) + compile-time imms.
__device__ __forceinline__ void rd_af(bf16x8 (&dst)[2][2], const unsigned short* src,
                                      int q, int aoff0, int aoff1) {
#pragma unroll
  for (int mi = 0; mi < 2; ++mi) {
    dst[mi][0] = *(const bf16x8*)(src + aoff0 + (q * 2 + mi) * 1024);
    dst[mi][1] = *(const bf16x8*)(src + aoff1 + (q * 2 + mi) * 1024);
  }
}

__device__ __forceinline__ void rd_bn2(bf16x8 (&dst)[4][2], const unsigned short* src,
                                       int n0, int boff0, int boff1) {
#pragma unroll
  for (int ni = 0; ni < 2; ++ni) {
    dst[n0 + ni][0] = *(const bf16x8*)(src + boff0 + (n0 + ni) * 1024);
    dst[n0 + ni][1] = *(const bf16x8*)(src + boff1 + (n0 + ni) * 1024);
  }
}

__device__ __forceinline__ void rd_b_all(bf16x8 (&dst)[4][2], const unsigned short* src,
                                         int boff0, int boff1) {
#pragma unroll
  for (int ni = 0; ni < 4; ++ni) {
    dst[ni][0] = *(const bf16x8*)(src + boff0 + ni * 1024);
    dst[ni][1] = *(const bf16x8*)(src + boff1 + ni * 1024);
  }
}

__device__ __forceinline__ void mma_q(floatx4 (&acc)[8][4], const bf16x8 (&af)[2][2],
                                      const bf16x8 (&b)[4][2], int q) {
  __builtin_amdgcn_s_setprio(1);
#pragma unroll
  for (int mi = 0; mi < 2; ++mi)
#pragma unroll
    for (int ni = 0; ni < 4; ++ni)
#pragma unroll
      for (int kk = 0; kk < 2; ++kk)
        acc[q * 2 + mi][ni] = __builtin_amdgcn_mfma_f32_16x16x32_bf16(
            af[mi][kk], b[ni][kk], acc[q * 2 + mi][ni], 0, 0, 0);
  __builtin_amdgcn_s_setprio(0);
}

template <bool SA, bool SB>
__device__ __forceinline__ void k_tile(
    const unsigned short* Asc,   // current A tile (LDS)
    unsigned short* Asn,         // next A tile: stage dst + P3 read src
    const unsigned short* Bsn,   // B(t+1) read src (LDS)
    unsigned short* Bsw,         // B(t+2) stage dst (LDS, = current B buf, dead)
    const unsigned short* gA, const Offs& oA,
    const unsigned short* gB, const Offs& oB,
    bf16x8 (&af_in)[2][2], bf16x8 (&bc)[4][2], bf16x8 (&bn)[4][2],
    floatx4 (&acc)[8][4],
    int aoff0, int aoff1, int boff0, int boff1, int w) {
  bf16x8 af_t[2][2];
  // ---- P0 ----
  rd_af(af_t, Asc, 1, aoff0, aoff1);
  if (SA) { stage_slot(gA, oA.o0, Asn, 0, w); stage_slot(gA, oA.o1, Asn, 1, w); }
  __builtin_amdgcn_s_barrier();
  mma_q(acc, af_in, bc, 0);
  __builtin_amdgcn_s_barrier();
  // ---- P1 ----
  rd_af(af_in, Asc, 2, aoff0, aoff1);
  if (SA) { stage_slot(gA, oA.o2, Asn, 2, w); stage_slot(gA, oA.o3, Asn, 3, w); }
  __builtin_amdgcn_s_barrier();
  mma_q(acc, af_t, bc, 1);
  if (SA) asm volatile("s_waitcnt vmcnt(4)" ::: "memory");
  __builtin_amdgcn_s_barrier();
  __builtin_amdgcn_sched_barrier(0);
  // ---- P2 ----
  rd_af(af_t, Asc, 3, aoff0, aoff1);
  if (SA) rd_bn2(bn, Bsn, 0, boff0, boff1);
  if (SB) { stage_slot(gB, oB.o0, Bsw, 0, w); stage_slot(gB, oB.o1, Bsw, 1, w); }
  __builtin_amdgcn_s_barrier();
  mma_q(acc, af_in, bc, 2);
  if (SB)      asm volatile("s_waitcnt vmcnt(2)" ::: "memory");
  else if (SA) asm volatile("s_waitcnt vmcnt(0)" ::: "memory");
  __builtin_amdgcn_s_barrier();
  __builtin_amdgcn_sched_barrier(0);
  // ---- P3 ----
  if (SA) { rd_af(af_in, Asn, 0, aoff0, aoff1); rd_bn2(bn, Bsn, 2, boff0, boff1); }
  if (SB) { stage_slot(gB, oB.o2, Bsw, 2, w); stage_slot(gB, oB.o3, Bsw, 3, w); }
  __builtin_amdgcn_s_barrier();
  mma_q(acc, af_t, bc, 3);
  __builtin_amdgcn_s_barrier();
}

// XCD-grouped swizzle: give each XCD a contiguous band of M-tiles across all
// N-tiles so A-panels get L2 reuse. gm must be a multiple of 8 (C >= 2048).
__device__ __forceinline__ void swizzle(int b, int gm, int gn, int& m, int& n) {
  const int xcd = b & 7;
  const int idx = b >> 3;
  const int mloc = idx / gn;
  n = idx - mloc * gn;
  m = xcd * (gm >> 3) + mloc;
}

// - GEMM1 fused: Hl/Hh[t,f] = scale * gelu(x.W1^T + b1), scale = (1-p) or p --
__global__ __launch_bounds__(512, 2) void gemm1_fused_kernel(
    const unsigned short* __restrict__ Xb,   // [C, H] bf16
    const unsigned short* __restrict__ W1l,  // [1280, H] bf16 (rows>=1152 junk)
    const unsigned short* __restrict__ W1h,  // [4608, H] bf16
    const float* __restrict__ b1l,           // [FL] fp32
    const float* __restrict__ b1h,           // [FH] fp32
    const float* __restrict__ p1,            // [C]
    unsigned short* __restrict__ Hl,         // [C, FL] bf16
    unsigned short* __restrict__ Hh,         // [C, FH] bf16
    int gm) {
  __shared__ __align__(16) unsigned short As[2][256 * 64];
  __shared__ __align__(16) unsigned short Bs[2][256 * 64];
  const int tid = threadIdx.x;
  const int w = tid >> 6, lane = tid & 63;
  const int wm = w >> 2, wn = w & 3;
  const int quad = lane >> 4, l16 = lane & 15;

  int m, n;
  swizzle(blockIdx.x, gm, 23, m, n);       // 5 light (padded) + 18 heavy
  const int tm = m * 256;
  const bool heavy = n >= 5;
  const int tn = (heavy ? n - 5 : n) * 256;

  const unsigned short* Ab = Xb + (size_t)tm * H_DIM;
  const unsigned short* Bb = (heavy ? W1h : W1l) + (size_t)tn * H_DIM;
  const Offs off = make_offs(tid, H_DIM);

  const int arow = wm * 128 + l16;
  const int brow = wn * 64 + l16;
  const int ch0 = quad ^ (l16 & 7);
  const int ch1 = ch0 ^ 4;
  const int aoff0 = arow * 64 + ch0 * 8;
  const int aoff1 = arow * 64 + ch1 * 8;
  const int boff0 = brow * 64 + ch0 * 8;
  const int boff1 = brow * 64 + ch1 * 8;

  unsigned short* As0 = &As[0][0];
  unsigned short* As1 = &As[1][0];
  unsigned short* Bs0 = &Bs[0][0];
  unsigned short* Bs1 = &Bs[1][0];

  floatx4 acc[8][4];
#pragma unroll
  for (int i = 0; i < 8; ++i)
#pragma unroll
    for (int j = 0; j < 4; ++j) acc[i][j] = (floatx4){0.f, 0.f, 0.f, 0.f};
  bf16x8 af_in[2][2], b0[4][2], b1f[4][2];

  // prologue: A(0), B(0) -> buf0; B(1) -> buf1; keep B(1)'s 4 in flight
  stage4(Ab, off, As0, w);
  stage4(Bb, off, Bs0, w);
  stage4(Bb + 64, off, Bs1, w);
  asm volatile("s_waitcnt vmcnt(4)" ::: "memory");
  __builtin_amdgcn_s_barrier();
  __builtin_amdgcn_sched_barrier(0);
  rd_af(af_in, As0, 0, aoff0, aoff1);
  rd_b_all(b0, Bs0, boff0, boff1);

  const int NT = H_DIM / 64;  // 18 (even)
  for (int t = 0; t + 3 < NT; t += 2) {
    k_tile<true, true>(As0, As1, Bs1, Bs0, Ab + (t + 1) * 64, off,
                       Bb + (t + 2) * 64, off, af_in, b0, b1f, acc,
                       aoff0, aoff1, boff0, boff1, w);
    k_tile<true, true>(As1, As0, Bs0, Bs1, Ab + (t + 2) * 64, off,
                       Bb + (t + 3) * 64, off, af_in, b1f, b0, acc,
                       aoff0, aoff1, boff0, boff1, w);
  }
  k_tile<true, false>(As0, As1, Bs1, Bs0, Ab + (NT - 1) * 64, off,
                      nullptr, off, af_in, b0, b1f, acc,
                      aoff0, aoff1, boff0, boff1, w);
  k_tile<false, false>(As1, As0, Bs0, Bs1, nullptr, off,
                       nullptr, off, af_in, b1f, b0, acc,
                       aoff0, aoff1, boff0, boff1, w);

  const int colb = tn + wn * 64 + l16;
  const int trow = tm + wm * 128 + quad * 4;
  if (heavy) {
    float bias[4];
#pragma unroll
    for (int ni = 0; ni < 4; ++ni) bias[ni] = b1h[colb + ni * 16];
#pragma unroll
    for (int mi = 0; mi < 8; ++mi)
#pragma unroll
      for (int r = 0; r < 4; ++r) {
        const int gtok = trow + mi * 16 + r;
        const float pv = p1[gtok];
#pragma unroll
        for (int ni = 0; ni < 4; ++ni) {
          const float v = acc[mi][ni][r] + bias[ni];
          const float g = 0.5f * v * (1.f + erff(v * 0.70710678118f));
          Hh[(size_t)gtok * FH_DIM + colb + ni * 16] = f2bf(g * pv);
        }
      }
  } else {
    float bias[4];
#pragma unroll
    for (int ni = 0; ni < 4; ++ni) {
      const int col = colb + ni * 16;
      bias[ni] = (col < FL_DIM) ? b1l[col] : 0.f;
    }
#pragma unroll
    for (int mi = 0; mi < 8; ++mi)
#pragma unroll
      for (int r = 0; r < 4; ++r) {
        const int gtok = trow + mi * 16 + r;
        const float pv = p1[gtok];
        const float sc = 1.f - pv;
#pragma unroll
        for (int ni = 0; ni < 4; ++ni) {
          const int col = colb + ni * 16;
          if (col < FL_DIM) {
            const float v = acc[mi][ni][r] + bias[ni];
            const float g = 0.5f * v * (1.f + erff(v * 0.70710678118f));
            Hl[(size_t)gtok * FL_DIM + col] = f2bf(g * sc);
          }
        }
      }
  }
}

// -- GEMM2: out[t,h] = Hl.W2l^T + Hh.W2h^T + (1-p1)b2l + p1*b2h (K = 5760) ---
__global__ __launch_bounds__(512, 2) void gemm2_kernel(
    const unsigned short* __restrict__ Hl,   // [C, FL] bf16
    const unsigned short* __restrict__ Hh,   // [C, FH] bf16
    const unsigned short* __restrict__ W2l,  // [1280, FL] bf16 (rows>=1152 junk)
    const unsigned short* __restrict__ W2h,  // [1280, FH] bf16
    const float* __restrict__ b2l,           // [H] fp32
    const float* __restrict__ b2h,           // [H] fp32
    const float* __restrict__ p1,            // [C]
    float* __restrict__ Out,                 // [C, H] fp32
    int gm) {
  __shared__ __align__(16) unsigned short As[2][256 * 64];
  __shared__ __align__(16) unsigned short Bs[2][256 * 64];
  const int tid = threadIdx.x;
  const int w = tid >> 6, lane = tid & 63;
  const int wm = w >> 2, wn = w & 3;
  const int quad = lane >> 4, l16 = lane & 15;

  int m, n;
  swizzle(blockIdx.x, gm, 5, m, n);        // N padded 1152 -> 1280
  const int tm = m * 256;
  const int tn = n * 256;

  const unsigned short* AL = Hl + (size_t)tm * FL_DIM;
  const unsigned short* AH = Hh + (size_t)tm * FH_DIM;
  const unsigned short* BL = W2l + (size_t)tn * FL_DIM;
  const unsigned short* BH = W2h + (size_t)tn * FH_DIM;
  const Offs offL = make_offs(tid, FL_DIM);
  const Offs offH = make_offs(tid, FH_DIM);

  const int KT1 = FL_DIM / 64;             // 18
  const int NT = KT1 + FH_DIM / 64;        // 90 (even)

  auto gAt = [&](int t) -> const unsigned short* {
    return (t < KT1) ? AL + t * 64 : AH + (size_t)(t - KT1) * 64;
  };
  auto gBt = [&](int t) -> const unsigned short* {
    return (t < KT1) ? BL + t * 64 : BH + (size_t)(t - KT1) * 64;
  };

  const int arow = wm * 128 + l16;
  const int brow = wn * 64 + l16;
  const int ch0 = quad ^ (l16 & 7);
  const int ch1 = ch0 ^ 4;
  const int aoff0 = arow * 64 + ch0 * 8;
  const int aoff1 = arow * 64 + ch1 * 8;
  const int boff0 = brow * 64 + ch0 * 8;
  const int boff1 = brow * 64 + ch1 * 8;

  unsigned short* As0 = &As[0][0];
  unsigned short* As1 = &As[1][0];
  unsigned short* Bs0 = &Bs[0][0];
  unsigned short* Bs1 = &Bs[1][0];

  floatx4 acc[8][4];
#pragma unroll
  for (int i = 0; i < 8; ++i)
#pragma unroll
    for (int j = 0; j < 4; ++j) acc[i][j] = (floatx4){0.f, 0.f, 0.f, 0.f};
  bf16x8 af_in[2][2], b0[4][2], b1f[4][2];

  stage4(gAt(0), offL, As0, w);
  stage4(gBt(0), offL, Bs0, w);
  stage4(gBt(1), offL, Bs1, w);
  asm volatile("s_waitcnt vmcnt(4)" ::: "memory");
  __builtin_amdgcn_s_barrier();
  __builtin_amdgcn_sched_barrier(0);
  rd_af(af_in, As0, 0, aoff0, aoff1);
  rd_b_all(b0, Bs0, boff0, boff1);

  for (int t = 0; t + 3 < NT; t += 2) {
    k_tile<true, true>(As0, As1, Bs1, Bs0,
                       gAt(t + 1), (t + 1 < KT1) ? offL : offH,
                       gBt(t + 2), (t + 2 < KT1) ? offL : offH,
                       af_in, b0, b1f, acc, aoff0, aoff1, boff0, boff1, w);
    k_tile<true, true>(As1, As0, Bs0, Bs1,
                       gAt(t + 2), (t + 2 < KT1) ? offL : offH,
                       gBt(t + 3), (t + 3 < KT1) ? offL : offH,
                       af_in, b1f, b0, acc, aoff0, aoff1, boff0, boff1, w);
  }
  k_tile<true, false>(As0, As1, Bs1, Bs0, gAt(NT - 1), offH,
                      nullptr, offH, af_in, b0, b1f, acc,
                      aoff0, aoff1, boff0, boff1, w);
  k_tile<false, false>(As1, As0, Bs0, Bs1, nullptr, offH,
                       nullptr, offH, af_in, b1f, b0, acc,
                       aoff0, aoff1, boff0, boff1, w);

  const int colb = tn + wn * 64 + l16;
  const int trow = tm + wm * 128 + quad * 4;
  float bl[4], bh[4];
#pragma unroll
  for (int ni = 0; ni < 4; ++ni) {
    const int col = colb + ni * 16;
    const bool ok = col < H_DIM;
    bl[ni] = ok ? b2l[col] : 0.f;
    bh[ni] = ok ? b2h[col] : 0.f;
  }
#pragma unroll
  for (int mi = 0; mi < 8; ++mi)
#pragma unroll
    for (int r = 0; r < 4; ++r) {
      const int gtok = trow + mi * 16 + r;
      const float pv = p1[gtok];
#pragma unroll
      for (int ni = 0; ni < 4; ++ni) {
        const int col = colb + ni * 16;
        if (col < H_DIM)
          Out[(size_t)gtok * H_DIM + col] = acc[mi][ni][r] + bl[ni] + pv * (bh[ni] - bl[ni]);
      }
    }
}

extern "C" void kernel_launch(void* const* d_in, const int* in_sizes, int n_in,
                              void* d_out, int out_size, void* d_ws, size_t ws_size,
                              hipStream_t stream) {
  const float* x   = (const float*)d_in[0];
  const float* rw  = (const float*)d_in[1];
  const float* rb  = (const float*)d_in[2];
  const float* lw1 = (const float*)d_in[3];
  const float* lb1 = (const float*)d_in[4];
  const float* lw2 = (const float*)d_in[5];
  const float* lb2 = (const float*)d_in[6];
  const float* hw1 = (const float*)d_in[7];
  const float* hb1 = (const float*)d_in[8];
  const float* hw2 = (const float*)d_in[9];
  const float* hb2 = (const float*)d_in[10];
  float* out = (float*)d_out;

  // ---- workspace layout (padded weight buffers for 256-wide N-tiles) ----
  const size_t N_LW1 = (size_t)FL_PAD * H_DIM;   // [1280,1152]
  const size_t N_HW1 = (size_t)FH_DIM * H_DIM;   // [4608,1152]
  const size_t N_LW2 = (size_t)H_PAD * FL_DIM;   // [1280,1152]
  const size_t N_HW2 = (size_t)H_PAD * FH_DIM;   // [1280,4608]
  char* p = (char*)d_ws;
  float* p1 = (float*)p;                     p += (size_t)NTOK * 4;
  unsigned short* lw1b = (unsigned short*)p; p += N_LW1 * 2;
  unsigned short* hw1b = (unsigned short*)p; p += N_HW1 * 2;
  unsigned short* lw2b = (unsigned short*)p; p += N_LW2 * 2;
  unsigned short* hw2b = (unsigned short*)p; p += N_HW2 * 2;
  unsigned short* xb   = (unsigned short*)p; p += (size_t)NTOK * H_DIM * 2;
  const size_t fixed = (size_t)(p - (char*)d_ws);

  // tokens per chunk: hl (C*FL*2) + hh (C*FH*2) = C*11520 bytes; C % 256 == 0
  int C = NTOK;
  while (C > 2048 && fixed + (size_t)C * 11520 > ws_size) C >>= 1;
  unsigned short* hl = (unsigned short*)p;
  unsigned short* hh = hl + (size_t)C * FL_DIM;

  // ---- weight conversions (fp32 -> bf16; real rows only, pad rows junk) ----
  cvt_kernel<<<(int)((size_t)FL_DIM * H_DIM / 1024), 256, 0, stream>>>(
      lw1, lw1b, (int)((size_t)FL_DIM * H_DIM / 4));
  cvt_kernel<<<(int)((size_t)FH_DIM * H_DIM / 1024), 256, 0, stream>>>(
      hw1, hw1b, (int)((size_t)FH_DIM * H_DIM / 4));
  cvt_kernel<<<(int)((size_t)H_DIM * FL_DIM / 1024), 256, 0, stream>>>(
      lw2, lw2b, (int)((size_t)H_DIM * FL_DIM / 4));
  cvt_kernel<<<(int)((size_t)H_DIM * FH_DIM / 1024), 256, 0, stream>>>(
      hw2, hw2b, (int)((size_t)H_DIM * FH_DIM / 4));

  router_cvt_kernel<<<NTOK / 4, 256, 0, stream>>>(x, rw, rb, p1, xb);

  for (int c0 = 0; c0 < NTOK; c0 += C) {
    const int gm = C / 256;
    gemm1_fused_kernel<<<gm * 23, 512, 0, stream>>>(
        xb + (size_t)c0 * H_DIM, lw1b, hw1b, lb1, hb1, p1 + c0, hl, hh, gm);
    gemm2_kernel<<<gm * 5, 512, 0, stream>>>(
        hl, hh, lw2b, hw2b, lb2, hb2, p1 + c0, out + (size_t)c0 * H_DIM, gm);
  }
}

// Round 3
// 1301.730 us; speedup vs baseline: 1.3521x; 1.3521x over previous
//
#include <hip/hip_runtime.h>
#include <hip/hip_bf16.h>
#include <math.h>

#define H_DIM  1152
#define FL_DIM 1152
#define FH_DIM 4608
#define NTOK   32768

typedef __attribute__((ext_vector_type(8))) short bf16x8;
typedef __attribute__((ext_vector_type(4))) float floatx4;
typedef __attribute__((ext_vector_type(4))) unsigned short ushort4v;

__device__ __forceinline__ unsigned short f2bf(float f) {
  union { float f; unsigned int i; } v; v.f = f;
  return (unsigned short)((v.i + 0x7FFFu + ((v.i >> 16) & 1u)) >> 16);
}

// ---------------- fp32 -> bf16 conversion (weights) -------------------------
__global__ __launch_bounds__(256) void cvt_kernel(
    const float* __restrict__ in, unsigned short* __restrict__ out, int n4) {
  const int i = blockIdx.x * 256 + threadIdx.x;
  if (i >= n4) return;
  const float4 v = ((const float4*)in)[i];
  ushort4v o;
  o[0] = f2bf(v.x); o[1] = f2bf(v.y); o[2] = f2bf(v.z); o[3] = f2bf(v.w);
  ((ushort4v*)out)[i] = o;
}

// ------- router + x cvt: p1[t] = sigmoid(l1-l0); xb = bf16(x) ---------------
__global__ __launch_bounds__(256) void router_cvt_kernel(
    const float* __restrict__ x,   // [NTOK, H] fp32
    const float* __restrict__ rw,  // [2, H]
    const float* __restrict__ rb,  // [2]
    float* __restrict__ p1out,     // [NTOK]
    unsigned short* __restrict__ xb) {  // [NTOK, H] bf16
  const int wave = threadIdx.x >> 6;
  const int lane = threadIdx.x & 63;
  const int tok = blockIdx.x * 4 + wave;
  const float* xr = x + (size_t)tok * H_DIM;
  unsigned short* xo = xb + (size_t)tok * H_DIM;
  float s0 = 0.f, s1 = 0.f;
#pragma unroll
  for (int j = 0; j < H_DIM / 64; ++j) {
    const int h = j * 64 + lane;
    const float xv = xr[h];
    xo[h] = f2bf(xv);
    s0 += xv * rw[h];
    s1 += xv * rw[H_DIM + h];
  }
  for (int off = 32; off > 0; off >>= 1) {
    s0 += __shfl_down(s0, off);
    s1 += __shfl_down(s1, off);
  }
  if (lane == 0) {
    const float l0 = s0 + rb[0];
    const float l1 = s1 + rb[1];
    p1out[tok] = 1.f / (1.f + expf(l0 - l1));
  }
}

// ------------- shared GEMM building blocks (128x128 tile, BK=64) -------------
// LDS: 128 rows x 8 chunks of 16B; chunk column XOR-swizzled by (row&7) so the
// ds_read_b128 fragment reads are 2-way bank-aliased (free) instead of 16-way.
// global_load_lds destination is wave-uniform base + lane*16 (HW requirement).
// LDA is a template parameter so row*LDA folds to shifts/adds at compile time
// and the whole chunk-offset computation is loop-invariant (hoisted by LICM);
// the per-K-step cost is one pointer increment per chunk.
template <int LDA>
__device__ __forceinline__ void stage_tile(const unsigned short* __restrict__ g0,
                                           unsigned short* l0, int tid) {
  const int w = tid >> 6;
#pragma unroll
  for (int i = 0; i < 4; ++i) {
    const int c = i * 256 + tid;     // linear 16B-chunk index, 1024 total
    const int row = c >> 3;
    const int jg = (c & 7) ^ (row & 7);
    const unsigned short* g = g0 + (size_t)row * LDA + jg * 8;
    unsigned short* lp = l0 + (size_t)(i * 4 + w) * 512;  // wave-uniform base
    __builtin_amdgcn_global_load_lds((const __attribute__((address_space(1))) void*)g,
                                     (__attribute__((address_space(3))) void*)lp,
                                     16, 0, 0);
  }
}

__device__ __forceinline__ void mma_tile(const unsigned short* As, const unsigned short* Bs,
                                         floatx4 acc[4][4], int wm, int wn, int quad, int l16) {
#pragma unroll
  for (int kk = 0; kk < 2; ++kk) {
    bf16x8 af[4], bfr[4];
#pragma unroll
    for (int mi = 0; mi < 4; ++mi) {
      const int row = wm * 64 + mi * 16 + l16;
      const int ch = (kk * 4 + quad) ^ (row & 7);
      af[mi] = *(const bf16x8*)(As + row * 64 + ch * 8);
    }
#pragma unroll
    for (int ni = 0; ni < 4; ++ni) {
      const int row = wn * 64 + ni * 16 + l16;
      const int ch = (kk * 4 + quad) ^ (row & 7);
      bfr[ni] = *(const bf16x8*)(Bs + row * 64 + ch * 8);
    }
#pragma unroll
    for (int mi = 0; mi < 4; ++mi)
#pragma unroll
      for (int ni = 0; ni < 4; ++ni)
        acc[mi][ni] = __builtin_amdgcn_mfma_f32_16x16x32_bf16(af[mi], bfr[ni], acc[mi][ni], 0, 0, 0);
  }
}

// XCD-grouped swizzle: consecutive block IDs round-robin over 8 XCDs, so give
// each XCD a contiguous band of M-tiles across all N-tiles. All N-tiles of a
// given M-tile then run on ONE XCD, adjacent in time -> A-tile L2/LLC reuse.
__device__ __forceinline__ void swizzle(int b, int gm, int gn, int& m, int& n) {
  const int xcd = b & 7;
  const int idx = b >> 3;
  const int mloc = idx / gn;
  n = idx - mloc * gn;
  m = xcd * (gm >> 3) + mloc;
}

// - GEMM1 fused: Hl/Hh[t,f] = scale * gelu(x.W1^T + b1), scale = (1-p) or p --
__global__ __launch_bounds__(256, 2) void gemm1_fused_kernel(
    const unsigned short* __restrict__ Xb,   // [C, H] bf16
    const unsigned short* __restrict__ W1l,  // [FL, H] bf16
    const unsigned short* __restrict__ W1h,  // [FH, H] bf16
    const float* __restrict__ b1l,           // [FL] fp32
    const float* __restrict__ b1h,           // [FH] fp32
    const float* __restrict__ p1,            // [C]
    unsigned short* __restrict__ Hl,         // [C, FL] bf16
    unsigned short* __restrict__ Hh,         // [C, FH] bf16
    int gm) {
  __shared__ __align__(16) unsigned short As[128 * 64];
  __shared__ __align__(16) unsigned short Bs[128 * 64];
  const int tid = threadIdx.x;
  const int w = tid >> 6, lane = tid & 63;
  const int wm = w >> 1, wn = w & 1;
  const int quad = lane >> 4, l16 = lane & 15;

  int m, n;
  swizzle(blockIdx.x, gm, 45, m, n);           // 9 light + 36 heavy N-tiles
  const int tm = m * 128;
  const bool heavy = n >= 9;
  const int nl = heavy ? n - 9 : n;
  const int tn = nl * 128;
  const int F = heavy ? FH_DIM : FL_DIM;
  const unsigned short* W = heavy ? W1h : W1l;
  const float* bias_p = heavy ? b1h : b1l;
  unsigned short* Hout = heavy ? Hh : Hl;

  floatx4 acc[4][4];
#pragma unroll
  for (int i = 0; i < 4; ++i)
#pragma unroll
    for (int j = 0; j < 4; ++j) acc[i][j] = (floatx4){0.f, 0.f, 0.f, 0.f};

  const unsigned short* Abase = Xb + (size_t)tm * H_DIM;
  const unsigned short* Bbase = W + (size_t)tn * H_DIM;

  for (int kt = 0; kt < H_DIM / 64; ++kt) {
    __syncthreads();
    stage_tile<H_DIM>(Abase + kt * 64, As, tid);
    stage_tile<H_DIM>(Bbase + kt * 64, Bs, tid);
    __syncthreads();
    mma_tile(As, Bs, acc, wm, wn, quad, l16);
  }

  float bias[4];
#pragma unroll
  for (int ni = 0; ni < 4; ++ni) bias[ni] = bias_p[tn + wn * 64 + ni * 16 + l16];

#pragma unroll
  for (int mi = 0; mi < 4; ++mi) {
#pragma unroll
    for (int r = 0; r < 4; ++r) {
      const int gtok = tm + wm * 64 + mi * 16 + quad * 4 + r;
      const float pv = p1[gtok];
      const float scale = heavy ? pv : (1.f - pv);
#pragma unroll
      for (int ni = 0; ni < 4; ++ni) {
        const int col = tn + wn * 64 + ni * 16 + l16;
        const float v = acc[mi][ni][r] + bias[ni];
        const float g = 0.5f * v * (1.f + erff(v * 0.70710678118f));
        Hout[(size_t)gtok * F + col] = f2bf(g * scale);
      }
    }
  }
}

// -- GEMM2: out[t,h] = Hl.W2l^T + Hh.W2h^T + (1-p1)b2l + p1*b2h (K = 5760) ---
// K-loop split into light (18 steps, lda=1152) and heavy (72 steps, lda=4608)
// loops so the staging addressing is fully hoisted per loop and there is no
// per-K-step branch. Sync structure identical to the fused-K version.
__global__ __launch_bounds__(256, 2) void gemm2_kernel(
    const unsigned short* __restrict__ Hl,   // [C, FL] bf16
    const unsigned short* __restrict__ Hh,   // [C, FH] bf16
    const unsigned short* __restrict__ W2l,  // [H, FL] bf16
    const unsigned short* __restrict__ W2h,  // [H, FH] bf16
    const float* __restrict__ b2l,           // [H] fp32
    const float* __restrict__ b2h,           // [H] fp32
    const float* __restrict__ p1,            // [C]
    float* __restrict__ Out,                 // [C, H] fp32
    int gm) {
  __shared__ __align__(16) unsigned short As[128 * 64];
  __shared__ __align__(16) unsigned short Bs[128 * 64];
  const int tid = threadIdx.x;
  const int w = tid >> 6, lane = tid & 63;
  const int wm = w >> 1, wn = w & 1;
  const int quad = lane >> 4, l16 = lane & 15;

  int m, n;
  swizzle(blockIdx.x, gm, 9, m, n);
  const int tm = m * 128;
  const int tn = n * 128;

  floatx4 acc[4][4];
#pragma unroll
  for (int i = 0; i < 4; ++i)
#pragma unroll
    for (int j = 0; j < 4; ++j) acc[i][j] = (floatx4){0.f, 0.f, 0.f, 0.f};

  {
    const unsigned short* Ab = Hl + (size_t)tm * FL_DIM;
    const unsigned short* Bb = W2l + (size_t)tn * FL_DIM;
    for (int kt = 0; kt < FL_DIM / 64; ++kt) {      // 18 light K-steps
      __syncthreads();
      stage_tile<FL_DIM>(Ab + kt * 64, As, tid);
      stage_tile<FL_DIM>(Bb + kt * 64, Bs, tid);
      __syncthreads();
      mma_tile(As, Bs, acc, wm, wn, quad, l16);
    }
  }
  {
    const unsigned short* Ab = Hh + (size_t)tm * FH_DIM;
    const unsigned short* Bb = W2h + (size_t)tn * FH_DIM;
    for (int kt = 0; kt < FH_DIM / 64; ++kt) {      // 72 heavy K-steps
      __syncthreads();
      stage_tile<FH_DIM>(Ab + kt * 64, As, tid);
      stage_tile<FH_DIM>(Bb + kt * 64, Bs, tid);
      __syncthreads();
      mma_tile(As, Bs, acc, wm, wn, quad, l16);
    }
  }

  float bl[4], bh[4];
#pragma unroll
  for (int ni = 0; ni < 4; ++ni) {
    const int col = tn + wn * 64 + ni * 16 + l16;
    bl[ni] = b2l[col];
    bh[ni] = b2h[col];
  }

#pragma unroll
  for (int mi = 0; mi < 4; ++mi) {
#pragma unroll
    for (int r = 0; r < 4; ++r) {
      const int gtok = tm + wm * 64 + mi * 16 + quad * 4 + r;
      const float pv = p1[gtok];
#pragma unroll
      for (int ni = 0; ni < 4; ++ni) {
        const int col = tn + wn * 64 + ni * 16 + l16;
        Out[(size_t)gtok * H_DIM + col] = acc[mi][ni][r] + bl[ni] + pv * (bh[ni] - bl[ni]);
      }
    }
  }
}

extern "C" void kernel_launch(void* const* d_in, const int* in_sizes, int n_in,
                              void* d_out, int out_size, void* d_ws, size_t ws_size,
                              hipStream_t stream) {
  const float* x   = (const float*)d_in[0];
  const float* rw  = (const float*)d_in[1];
  const float* rb  = (const float*)d_in[2];
  const float* lw1 = (const float*)d_in[3];
  const float* lb1 = (const float*)d_in[4];
  const float* lw2 = (const float*)d_in[5];
  const float* lb2 = (const float*)d_in[6];
  const float* hw1 = (const float*)d_in[7];
  const float* hb1 = (const float*)d_in[8];
  const float* hw2 = (const float*)d_in[9];
  const float* hb2 = (const float*)d_in[10];
  float* out = (float*)d_out;

  // ---- workspace layout ----
  const size_t N_LW = (size_t)FL_DIM * H_DIM;
  const size_t N_HW = (size_t)FH_DIM * H_DIM;
  char* p = (char*)d_ws;
  float* p1 = (float*)p;                     p += (size_t)NTOK * 4;
  unsigned short* lw1b = (unsigned short*)p; p += N_LW * 2;
  unsigned short* hw1b = (unsigned short*)p; p += N_HW * 2;
  unsigned short* lw2b = (unsigned short*)p; p += N_LW * 2;
  unsigned short* hw2b = (unsigned short*)p; p += N_HW * 2;
  unsigned short* xb   = (unsigned short*)p; p += (size_t)NTOK * H_DIM * 2;
  const size_t fixed = (size_t)(p - (char*)d_ws);

  // tokens per chunk: hl (C*FL*2) + hh (C*FH*2) = C*11520 bytes
  int C = NTOK;
  while (C > 1024 && fixed + (size_t)C * 11520 > ws_size) C >>= 1;
  unsigned short* hl = (unsigned short*)p;
  unsigned short* hh = hl + (size_t)C * FL_DIM;

  // ---- weight conversions (fp32 -> bf16) ----
  cvt_kernel<<<(int)(N_LW / 1024), 256, 0, stream>>>(lw1, lw1b, (int)(N_LW / 4));
  cvt_kernel<<<(int)(N_HW / 1024), 256, 0, stream>>>(hw1, hw1b, (int)(N_HW / 4));
  cvt_kernel<<<(int)(N_LW / 1024), 256, 0, stream>>>(lw2, lw2b, (int)(N_LW / 4));
  cvt_kernel<<<(int)(N_HW / 1024), 256, 0, stream>>>(hw2, hw2b, (int)(N_HW / 4));

  router_cvt_kernel<<<NTOK / 4, 256, 0, stream>>>(x, rw, rb, p1, xb);

  for (int c0 = 0; c0 < NTOK; c0 += C) {
    const int gm = C / 128;
    gemm1_fused_kernel<<<gm * 45, 256, 0, stream>>>(
        xb + (size_t)c0 * H_DIM, lw1b, hw1b, lb1, hb1, p1 + c0, hl, hh, gm);
    gemm2_kernel<<<gm * 9, 256, 0, stream>>>(
        hl, hh, lw2b, hw2b, lb2, hb2, p1 + c0, out + (size_t)c0 * H_DIM, gm);
  }
}